// Round 6
// baseline (267.350 us; speedup 1.0000x reference)
//
#include <hip/hip_runtime.h>
#include <math.h>

#define Bb 8
#define Nn 512
#define Mm 64
#define Dd 128
#define Hh 64
#define Gg 4                 // n's per block
#define NEG_BIG (-1.0e30f)

typedef __bf16 bf16x8 __attribute__((ext_vector_type(8)));
typedef float  f32x4  __attribute__((ext_vector_type(4)));

// ws byte offsets (16B-aligned)
#define WS_WEB   0u          // 16384 B  bf16 We B-frags, frag-linear [16 frag][64 lane][8]
#define WS_W2B   16384u      // 8192 B   bf16 W2 B-frags, frag-linear [8 frag][64 lane][8]
#define WS_CWS   24576u      // 131072 B fp32 Cws[b*M+m][h] (b1 folded)
#define WS_AOP   155648u     // 1048576 B fp32 Aop[b*N+n][h]
#define WS_SCORE 1204224u    // 1048576 B fp32 scores[b*N+n][m]
#define WS_PART  2252800u    // 4096 B   fp32 (max,sumexp) per 512-chunk [512][2]

// ---------- prep: weights -> bf16 B-frag stream, plus op/machine projections ----------
__global__ __launch_bounds__(256) void prep_kernel(
    const float* __restrict__ W1, const float* __restrict__ W2,
    const float* __restrict__ op_emb, const float* __restrict__ machine_emb,
    const float* __restrict__ b1, char* __restrict__ ws)
{
    if (blockIdx.x < 48) {               // weight fragment prep (12288 threads)
        __bf16* WeB = (__bf16*)(ws + WS_WEB);
        __bf16* W2B = (__bf16*)(ws + WS_W2B);
        int idx = blockIdx.x * 256 + threadIdx.x;
        if (idx < 8192) {                // We: 16 frags (t 0..3, ks 0..3)
            int fid = idx >> 9, rem = idx & 511;
            int lane = rem >> 3, j = rem & 7;
            int t = fid >> 2, ks = fid & 3;
            int q = lane >> 4, ln = lane & 15;
            int d = ks * 32 + q * 8 + j;
            int h = t * 16 + ln;
            WeB[idx] = (__bf16)W1[(size_t)(2 * Dd + d) * Hh + h];
        } else {                         // W2: 8 frags (t 0..3, ks 0..1)
            int i2 = idx - 8192;
            int fid = i2 >> 9, rem = i2 & 511;
            int lane = rem >> 3, j = rem & 7;
            int t = fid >> 1, ks = fid & 1;
            int q = lane >> 4, ln = lane & 15;
            int k = ks * 32 + q * 8 + j;
            int h = t * 16 + ln;
            W2B[i2] = (__bf16)W2[(size_t)k * Hh + h];
        }
        return;
    }
    // projections: 1152 blocks x 4 rows (B*M + B*N = 4608 rows of 64)
    float* Cws = (float*)(ws + WS_CWS);
    float* Aop = (float*)(ws + WS_AOP);
    const int bid = (blockIdx.x - 48) * 4 + (threadIdx.x >> 6);
    const int h = threadIdx.x & 63;
    if (bid < Bb * Mm) {
        const float* mg = machine_emb + (size_t)bid * Dd;
        const float* Wm = W1 + (size_t)Dd * Hh;
        float acc = b1[h];
#pragma unroll 8
        for (int d = 0; d < Dd; ++d) acc = fmaf(mg[d], Wm[d * Hh + h], acc);
        Cws[(size_t)bid * Hh + h] = acc;
    } else {
        const int bn = bid - Bb * Mm;
        const float* og = op_emb + (size_t)bn * Dd;
        float acc = 0.f;
#pragma unroll 8
        for (int d = 0; d < Dd; ++d) acc = fmaf(og[d], W1[d * Hh + h], acc);
        Aop[(size_t)bn * Hh + h] = acc;
    }
}

// ---------- main: zero barriers, LDS = sH1 only, weights from L1/L2 ----------
__global__ __launch_bounds__(256, 4) void main_kernel(
    const float* __restrict__ edge_emb, const int* __restrict__ mask,
    const float* __restrict__ b2, const float* __restrict__ W3,
    const float* __restrict__ b3, char* __restrict__ ws)
{
    __shared__ __bf16 sH1[Mm * 72];     // 9.2 KB, wave-private row tiles; only LDS use

    const __bf16* WeB = (const __bf16*)(ws + WS_WEB);
    const __bf16* W2B = (const __bf16*)(ws + WS_W2B);
    const float*  Cws = (const float*)(ws + WS_CWS);
    const float*  Aop = (const float*)(ws + WS_AOP);
    float* scores     = (float*)(ws + WS_SCORE);

    const int tid  = threadIdx.x;
    const int lane = tid & 63;
    const int w    = tid >> 6;
    const int q    = lane >> 4;
    const int ln   = lane & 15;
    const int bn0  = blockIdx.x * Gg;
    const int b    = bn0 >> 9;          // 128 blocks per batch; never straddles
    const int mrow = w * 16 + ln;

    // loop-invariant registers
    float cv[16];
#pragma unroll
    for (int t = 0; t < 4; ++t)
#pragma unroll
        for (int r = 0; r < 4; ++r)
            cv[t * 4 + r] = Cws[((size_t)b * Mm + w * 16 + q * 4 + r) * Hh + t * 16 + ln];
    float b2v[4], w3v[4];
#pragma unroll
    for (int t = 0; t < 4; ++t) { b2v[t] = b2[t * 16 + ln]; w3v[t] = W3[t * 16 + ln]; }
    const float bias3 = b3[0];

    // prefetch iteration 0: edge tile + Aop + mask
    float4 raw[8]; float aopv[4]; int4 mk = {0, 0, 0, 0};
    {
        const float* Eg = edge_emb + (size_t)bn0 * (Mm * Dd) + mrow * Dd + q * 8;
#pragma unroll
        for (int ks = 0; ks < 4; ++ks) {
            raw[2 * ks]     = *(const float4*)&Eg[ks * 32];
            raw[2 * ks + 1] = *(const float4*)&Eg[ks * 32 + 4];
        }
#pragma unroll
        for (int t = 0; t < 4; ++t) aopv[t] = Aop[(size_t)bn0 * Hh + t * 16 + ln];
        if (ln == 0) mk = *(const int4*)&mask[(size_t)bn0 * Mm + w * 16 + q * 4];
    }

#pragma unroll
    for (int g = 0; g < Gg; ++g) {
        const int bn = bn0 + g;

        // convert current tile to bf16 A-frags (consumes raw)
        bf16x8 af[4];
#pragma unroll
        for (int ks = 0; ks < 4; ++ks) {
            float4 lo = raw[2 * ks], hi = raw[2 * ks + 1];
            bf16x8 a;
            a[0] = (__bf16)lo.x; a[1] = (__bf16)lo.y; a[2] = (__bf16)lo.z; a[3] = (__bf16)lo.w;
            a[4] = (__bf16)hi.x; a[5] = (__bf16)hi.y; a[6] = (__bf16)hi.z; a[7] = (__bf16)hi.w;
            af[ks] = a;
        }
        // issue next tile's loads (overlap with both GEMMs)
        float naop[4] = {};
        int4  nmk = {0, 0, 0, 0};
        if (g + 1 < Gg) {
            const float* Eg = edge_emb + (size_t)(bn + 1) * (Mm * Dd) + mrow * Dd + q * 8;
#pragma unroll
            for (int ks = 0; ks < 4; ++ks) {
                raw[2 * ks]     = *(const float4*)&Eg[ks * 32];
                raw[2 * ks + 1] = *(const float4*)&Eg[ks * 32 + 4];
            }
#pragma unroll
            for (int t = 0; t < 4; ++t) naop[t] = Aop[(size_t)(bn + 1) * Hh + t * 16 + ln];
            if (ln == 0) nmk = *(const int4*)&mask[(size_t)(bn + 1) * Mm + w * 16 + q * 4];
        }

        // acc init = Aop[n,h] + Cws[m,h]
        f32x4 acc[4];
#pragma unroll
        for (int t = 0; t < 4; ++t)
#pragma unroll
            for (int r = 0; r < 4; ++r)
                acc[t][r] = aopv[t] + cv[t * 4 + r];

        // GEMM1: D = edge . We + (A+C); B-frags straight from L1/L2 (lane*16B)
#pragma unroll
        for (int t = 0; t < 4; ++t)
#pragma unroll
            for (int ks = 0; ks < 4; ++ks) {
                bf16x8 bfr = *(const bf16x8*)&WeB[((t * 4 + ks) * 64 + lane) * 8];
                acc[t] = __builtin_amdgcn_mfma_f32_16x16x32_bf16(af[ks], bfr, acc[t], 0, 0, 0);
            }

        // epilogue 1: relu -> sH1 (wave-private rows, no barrier)
#pragma unroll
        for (int t = 0; t < 4; ++t)
#pragma unroll
            for (int r = 0; r < 4; ++r)
                sH1[(w * 16 + q * 4 + r) * 72 + t * 16 + ln] =
                    (__bf16)fmaxf(acc[t][r], 0.f);

        // GEMM2
        bf16x8 a2[2];
#pragma unroll
        for (int ks = 0; ks < 2; ++ks)
            a2[ks] = *(const bf16x8*)&sH1[(w * 16 + ln) * 72 + ks * 32 + q * 8];
        f32x4 c2[4];
#pragma unroll
        for (int t = 0; t < 4; ++t) c2[t] = (f32x4){0.f, 0.f, 0.f, 0.f};
#pragma unroll
        for (int t = 0; t < 4; ++t)
#pragma unroll
            for (int ks = 0; ks < 2; ++ks) {
                bf16x8 bfr = *(const bf16x8*)&W2B[((t * 2 + ks) * 64 + lane) * 8];
                c2[t] = __builtin_amdgcn_mfma_f32_16x16x32_bf16(a2[ks], bfr, c2[t], 0, 0, 0);
            }

        // epilogue 2: masked scores
        float p[4] = {0.f, 0.f, 0.f, 0.f};
#pragma unroll
        for (int t = 0; t < 4; ++t)
#pragma unroll
            for (int r = 0; r < 4; ++r)
                p[r] += fmaxf(c2[t][r] + b2v[t], 0.f) * w3v[t];
#pragma unroll
        for (int r = 0; r < 4; ++r) {
            p[r] += __shfl_xor(p[r], 1, 64);
            p[r] += __shfl_xor(p[r], 2, 64);
            p[r] += __shfl_xor(p[r], 4, 64);
            p[r] += __shfl_xor(p[r], 8, 64);
        }
        if (ln == 0) {
            float4 o;
            o.x = mk.x ? (p[0] + bias3) : NEG_BIG;
            o.y = mk.y ? (p[1] + bias3) : NEG_BIG;
            o.z = mk.z ? (p[2] + bias3) : NEG_BIG;
            o.w = mk.w ? (p[3] + bias3) : NEG_BIG;
            *(float4*)&scores[(size_t)bn * Mm + w * 16 + q * 4] = o;
        }
#pragma unroll
        for (int t = 0; t < 4; ++t) aopv[t] = naop[t];
        mk = nmk;
    }
}

// ---------- log-softmax stage 1: per-512-chunk (max, sumexp) ----------
__global__ __launch_bounds__(256) void lsm_part_kernel(char* __restrict__ ws)
{
    const float* s = (const float*)(ws + WS_SCORE);
    float* part = (float*)(ws + WS_PART);
    __shared__ float sm[4], ss[4];
    const int c = blockIdx.x;            // 0..511
    const int tid = threadIdx.x;
    const int lane = tid & 63, wv = tid >> 6;

    float2 v = *(const float2*)&s[(size_t)c * 512 + tid * 2];
    float m = fmaxf(v.x, v.y);
#pragma unroll
    for (int off = 1; off < 64; off <<= 1) m = fmaxf(m, __shfl_xor(m, off, 64));
    if (lane == 0) sm[wv] = m;
    __syncthreads();
    float gm = fmaxf(fmaxf(sm[0], sm[1]), fmaxf(sm[2], sm[3]));

    float e = expf(v.x - gm) + expf(v.y - gm);
#pragma unroll
    for (int off = 1; off < 64; off <<= 1) e += __shfl_xor(e, off, 64);
    if (lane == 0) ss[wv] = e;
    __syncthreads();
    if (tid == 0) {
        float2 o; o.x = gm; o.y = ss[0] + ss[1] + ss[2] + ss[3];
        *(float2*)&part[c * 2] = o;
    }
}

// ---------- log-softmax stage 2: combine partials inline, apply ----------
__global__ __launch_bounds__(256) void lsm_apply_kernel(
    const char* __restrict__ ws, float* __restrict__ out)
{
    const float4* s4 = (const float4*)(ws + WS_SCORE);
    const float* part = (const float*)(ws + WS_PART);
    __shared__ float sCC;
    const int tid = threadIdx.x;
    const int b = blockIdx.x >> 5;       // 32 blocks per batch
    if (tid < 64) {                      // inline combine of 64 partials
        float2 p = *(const float2*)&part[(b * 64 + tid) * 2];
        float gm = p.x;
#pragma unroll
        for (int off = 1; off < 64; off <<= 1) gm = fmaxf(gm, __shfl_xor(gm, off, 64));
        float l = p.y * expf(p.x - gm);
#pragma unroll
        for (int off = 1; off < 64; off <<= 1) l += __shfl_xor(l, off, 64);
        if (tid == 0) sCC = gm + logf(l);
    }
    __syncthreads();
    const float c = sCC;
    const int i = blockIdx.x * 256 + tid;    // 65536 float4s
    float4 v = s4[i];
    v.x -= c; v.y -= c; v.z -= c; v.w -= c;
    ((float4*)out)[i] = v;
}

extern "C" void kernel_launch(void* const* d_in, const int* in_sizes, int n_in,
                              void* d_out, int out_size, void* d_ws, size_t ws_size,
                              hipStream_t stream)
{
    const float* op_emb      = (const float*)d_in[0];
    const float* machine_emb = (const float*)d_in[1];
    const float* edge_emb    = (const float*)d_in[2];
    const int*   mask        = (const int*)  d_in[3];
    const float* W1 = (const float*)d_in[4];
    const float* b1 = (const float*)d_in[5];
    const float* W2 = (const float*)d_in[6];
    const float* b2 = (const float*)d_in[7];
    const float* W3 = (const float*)d_in[8];
    const float* b3 = (const float*)d_in[9];
    char* ws = (char*)d_ws;

    prep_kernel<<<48 + 1152, 256, 0, stream>>>(W1, W2, op_emb, machine_emb, b1, ws);
    main_kernel<<<(Bb * Nn) / Gg, 256, 0, stream>>>(edge_emb, mask, b2, W3, b3, ws);
    lsm_part_kernel<<<512, 256, 0, stream>>>(ws);
    lsm_apply_kernel<<<256, 256, 0, stream>>>(ws, (float*)d_out);
}

// Round 8
// 233.511 us; speedup vs baseline: 1.1449x; 1.1449x over previous
//
#include <hip/hip_runtime.h>
#include <math.h>

#define Bb 8
#define Nn 512
#define Mm 64
#define Dd 128
#define Hh 64
#define Gg 16                // n's per block; grid = 4096/16 = 256 = 1 block/CU
#define NEG_BIG (-1.0e30f)

typedef __bf16 bf16x8 __attribute__((ext_vector_type(8)));
typedef float  f32x4  __attribute__((ext_vector_type(4)));

// ws byte offsets (16B-aligned)
#define WS_WEB   0u          // 16384 B  bf16 We B-frags, frag-linear [16 frag][64 lane][8]
#define WS_W2B   16384u      // 8192 B   bf16 W2 B-frags, frag-linear [8 frag][64 lane][8]
#define WS_CWSF  24576u      // 131072 B fp32 CwsF[b][w][t][lane][r] (b1 folded, frag-swizzled)
#define WS_AOP   155648u     // 1048576 B fp32 Aop[b*N+n][h]
#define WS_SCORE 1204224u    // 1048576 B fp32 scores[b*N+n][m]
#define WS_PART  2252800u    // 4096 B   fp32 (max,sumexp) per 512-chunk [512][2]

// async global->LDS DMA, 16B/lane; offset must be an ICE -> fold into gp, pass 0
#define GLOAD_LDS(gp, lp) __builtin_amdgcn_global_load_lds( \
    (const __attribute__((address_space(1))) void*)(gp),    \
    (__attribute__((address_space(3))) void*)(lp), 16, 0, 0)

// ---------- prep: weight B-frags + projections (CwsF frag-swizzled) ----------
__global__ __launch_bounds__(256) void prep_kernel(
    const float* __restrict__ W1, const float* __restrict__ W2,
    const float* __restrict__ op_emb, const float* __restrict__ machine_emb,
    const float* __restrict__ b1, char* __restrict__ ws)
{
    if (blockIdx.x < 48) {               // weight fragment prep
        __bf16* WeB = (__bf16*)(ws + WS_WEB);
        __bf16* W2B = (__bf16*)(ws + WS_W2B);
        int idx = blockIdx.x * 256 + threadIdx.x;
        if (idx < 8192) {                // We: 16 frags (t 0..3, ks 0..3)
            int fid = idx >> 9, rem = idx & 511;
            int lane = rem >> 3, j = rem & 7;
            int t = fid >> 2, ks = fid & 3;
            int q = lane >> 4, ln = lane & 15;
            int d = ks * 32 + q * 8 + j;
            int h = t * 16 + ln;
            WeB[idx] = (__bf16)W1[(size_t)(2 * Dd + d) * Hh + h];
        } else {                         // W2: 8 frags (t 0..3, ks 0..1)
            int i2 = idx - 8192;
            int fid = i2 >> 9, rem = i2 & 511;
            int lane = rem >> 3, j = rem & 7;
            int t = fid >> 1, ks = fid & 1;
            int q = lane >> 4, ln = lane & 15;
            int k = ks * 32 + q * 8 + j;
            int h = t * 16 + ln;
            W2B[i2] = (__bf16)W2[(size_t)k * Hh + h];
        }
        return;
    }
    // projections: 1152 blocks x 4 rows (B*M + B*N = 4608 rows of 64)
    float* CwsF = (float*)(ws + WS_CWSF);
    float* Aop  = (float*)(ws + WS_AOP);
    const int bid = (blockIdx.x - 48) * 4 + (threadIdx.x >> 6);
    const int h = threadIdx.x & 63;
    if (bid < Bb * Mm) {
        const float* mg = machine_emb + (size_t)bid * Dd;
        const float* Wm = W1 + (size_t)Dd * Hh;
        float acc = b1[h];
#pragma unroll 8
        for (int d = 0; d < Dd; ++d) acc = fmaf(mg[d], Wm[d * Hh + h], acc);
        // scatter into fragment order: [b][w][t][lane=q*16+ln][r]
        int b = bid >> 6, m = bid & 63;
        int wq = m >> 4, q = (m >> 2) & 3, r = m & 3;
        int t = h >> 4, ln = h & 15;
        CwsF[((((b * 4 + wq) * 4 + t) * 64) + (q * 16 + ln)) * 4 + r] = acc;
    } else {
        const int bn = bid - Bb * Mm;
        const float* og = op_emb + (size_t)bn * Dd;
        float acc = 0.f;
#pragma unroll 8
        for (int d = 0; d < Dd; ++d) acc = fmaf(og[d], W1[d * Hh + h], acc);
        Aop[(size_t)bn * Hh + h] = acc;
    }
}

// ---------- main: DMA-streamed edge, weights in regs, no in-loop barriers ----------
__global__ __launch_bounds__(256, 1) void main_kernel(
    const float* __restrict__ edge_emb, const int* __restrict__ mask,
    const float* __restrict__ b2, const float* __restrict__ W3,
    const float* __restrict__ b3, char* __restrict__ ws)
{
    __shared__ float  sEdge[4 * 2 * 2048];  // 65536 B: [wave][buf][seg 0..7][256 floats]
    __shared__ float  sCwsF[4096];          // 16384 B: [w][t][lane][4]
    __shared__ float  sAop[Gg * Hh];        //  4096 B
    __shared__ int    sMask[Gg * Mm];       //  4096 B
    __shared__ __bf16 sH1[Mm * 72];         //  9216 B  -> total 99328 B, 1 block/CU

    float* scores = (float*)(ws + WS_SCORE);

    const int tid  = threadIdx.x;
    const int lane = tid & 63;
    const int w    = tid >> 6;
    const int q    = lane >> 4;
    const int ln   = lane & 15;
    const int bn0  = blockIdx.x * Gg;
    const int b    = bn0 >> 9;              // 32 blocks per batch; never straddles
    const int wu   = __builtin_amdgcn_readfirstlane(w);   // SGPR wave id for LDS bases

    // per-lane global base: row m = w*16+ln, col q*8 (floats)
    const float* ebase = edge_emb + ((size_t)bn0 * Mm + w * 16 + ln) * Dd + q * 8;

    // ---- prologue DMAs: tiles g=0 -> buf0, g=1 -> buf1 (8 segs each) ----
    {
        float* d0 = &sEdge[(wu * 2 + 0) * 2048];
        float* d1 = &sEdge[(wu * 2 + 1) * 2048];
#pragma unroll
        for (int s = 0; s < 8; ++s)
            GLOAD_LDS(ebase + (s >> 1) * 32 + (s & 1) * 4, d0 + s * 256);
#pragma unroll
        for (int s = 0; s < 8; ++s)
            GLOAD_LDS(ebase + 8192 + (s >> 1) * 32 + (s & 1) * 4, d1 + s * 256);
    }

    // ---- one-time staging (linear/coalesced) ----
    {
        const f32x4* s3 = (const f32x4*)(ws + WS_CWSF) + (size_t)b * 1024;
        f32x4* d3 = (f32x4*)sCwsF;
#pragma unroll
        for (int i = 0; i < 4; ++i) d3[tid + 256 * i] = s3[tid + 256 * i];
        ((f32x4*)sAop)[tid]  = ((const f32x4*)((ws + WS_AOP)))[(size_t)bn0 * 16 + tid];
        ((int4*)sMask)[tid]  = ((const int4*)mask)[(size_t)bn0 * 16 + tid];
    }

    // ---- weights into registers (held whole kernel; no per-g weight loads) ----
    bf16x8 weF[16], w2F[8];
    {
        const bf16x8* WeB = (const bf16x8*)(ws + WS_WEB);
        const bf16x8* W2B = (const bf16x8*)(ws + WS_W2B);
#pragma unroll
        for (int f = 0; f < 16; ++f) weF[f] = WeB[f * 64 + lane];
#pragma unroll
        for (int f = 0; f < 8; ++f)  w2F[f] = W2B[f * 64 + lane];
    }

    float b2v[4], w3v[4];
#pragma unroll
    for (int t = 0; t < 4; ++t) { b2v[t] = b2[t * 16 + ln]; w3v[t] = W3[t * 16 + ln]; }
    const float bias3 = b3[0];

    __syncthreads();   // staging visible (drains prologue DMAs too)

#pragma unroll
    for (int g = 0; g < Gg; ++g) {
        const int buf = g & 1;
        const float* ldsrd = &sEdge[(wu * 2 + buf) * 2048];

        // drain only the tile being consumed; keep the in-flight refill pending.
        // vmcnt semantics (m135): waits for (outstanding - N) oldest ops.
        if (g == Gg - 1) __builtin_amdgcn_s_waitcnt(0x0F70);  // vmcnt(0) at tail
        else             __builtin_amdgcn_s_waitcnt(0x0F78);  // vmcnt(8)

        f32x4 lo[4], hi[4];
#pragma unroll
        for (int ks = 0; ks < 4; ++ks) {
            lo[ks] = *(const f32x4*)&ldsrd[(ks * 2 + 0) * 256 + lane * 4];
            hi[ks] = *(const f32x4*)&ldsrd[(ks * 2 + 1) * 256 + lane * 4];
        }
        bf16x8 af[4];
#pragma unroll
        for (int ks = 0; ks < 4; ++ks) {
            bf16x8 a;
            a[0] = (__bf16)lo[ks][0]; a[1] = (__bf16)lo[ks][1];
            a[2] = (__bf16)lo[ks][2]; a[3] = (__bf16)lo[ks][3];
            a[4] = (__bf16)hi[ks][0]; a[5] = (__bf16)hi[ks][1];
            a[6] = (__bf16)hi[ks][2]; a[7] = (__bf16)hi[ks][3];
            af[ks] = a;
        }

        // refill this buffer with tile g+2 (tile g's LDS reads issued above)
        if (g + 2 < Gg) {
            float* dst = &sEdge[(wu * 2 + buf) * 2048];
            const float* src = ebase + (size_t)(g + 2) * 8192;
#pragma unroll
            for (int s = 0; s < 8; ++s)
                GLOAD_LDS(src + (s >> 1) * 32 + (s & 1) * 4, dst + s * 256);
        }

        // acc init = Aop[n,h] + Cws[m,h] (frag-order b128 reads)
        f32x4 acc[4];
#pragma unroll
        for (int t = 0; t < 4; ++t) {
            f32x4 cv4 = *(const f32x4*)&sCwsF[((w * 4 + t) * 64 + lane) * 4];
            float av = sAop[g * Hh + t * 16 + ln];
            acc[t][0] = cv4[0] + av; acc[t][1] = cv4[1] + av;
            acc[t][2] = cv4[2] + av; acc[t][3] = cv4[3] + av;
        }

        // GEMM1: D = edge . We + (A+C)  (weights in regs)
#pragma unroll
        for (int t = 0; t < 4; ++t)
#pragma unroll
            for (int ks = 0; ks < 4; ++ks)
                acc[t] = __builtin_amdgcn_mfma_f32_16x16x32_bf16(af[ks], weF[t * 4 + ks], acc[t], 0, 0, 0);

        // epilogue 1: relu -> sH1 (wave-private rows, no barrier)
#pragma unroll
        for (int t = 0; t < 4; ++t)
#pragma unroll
            for (int r = 0; r < 4; ++r)
                sH1[(w * 16 + q * 4 + r) * 72 + t * 16 + ln] =
                    (__bf16)fmaxf(acc[t][r], 0.f);

        // GEMM2
        bf16x8 a2[2];
#pragma unroll
        for (int ks = 0; ks < 2; ++ks)
            a2[ks] = *(const bf16x8*)&sH1[(w * 16 + ln) * 72 + ks * 32 + q * 8];
        f32x4 c2[4];
#pragma unroll
        for (int t = 0; t < 4; ++t) c2[t] = (f32x4){0.f, 0.f, 0.f, 0.f};
#pragma unroll
        for (int t = 0; t < 4; ++t)
#pragma unroll
            for (int ks = 0; ks < 2; ++ks)
                c2[t] = __builtin_amdgcn_mfma_f32_16x16x32_bf16(a2[ks], w2F[t * 2 + ks], c2[t], 0, 0, 0);

        // epilogue 2: masked scores
        float p[4] = {0.f, 0.f, 0.f, 0.f};
#pragma unroll
        for (int t = 0; t < 4; ++t)
#pragma unroll
            for (int r = 0; r < 4; ++r)
                p[r] += fmaxf(c2[t][r] + b2v[t], 0.f) * w3v[t];
#pragma unroll
        for (int r = 0; r < 4; ++r) {
            p[r] += __shfl_xor(p[r], 1, 64);
            p[r] += __shfl_xor(p[r], 2, 64);
            p[r] += __shfl_xor(p[r], 4, 64);
            p[r] += __shfl_xor(p[r], 8, 64);
        }
        if (ln == 0) {
            const int m0 = w * 16 + q * 4;
            const int* mrow = &sMask[g * Mm + m0];
            float4 o;
            o.x = mrow[0] ? (p[0] + bias3) : NEG_BIG;
            o.y = mrow[1] ? (p[1] + bias3) : NEG_BIG;
            o.z = mrow[2] ? (p[2] + bias3) : NEG_BIG;
            o.w = mrow[3] ? (p[3] + bias3) : NEG_BIG;
            *(float4*)&scores[(size_t)(bn0 + g) * Mm + m0] = o;
        }
    }
}

// ---------- log-softmax stage 1: per-512-chunk (max, sumexp) ----------
__global__ __launch_bounds__(256) void lsm_part_kernel(char* __restrict__ ws)
{
    const float* s = (const float*)(ws + WS_SCORE);
    float* part = (float*)(ws + WS_PART);
    __shared__ float sm[4], ss[4];
    const int c = blockIdx.x;            // 0..511
    const int tid = threadIdx.x;
    const int lane = tid & 63, wv = tid >> 6;

    float2 v = *(const float2*)&s[(size_t)c * 512 + tid * 2];
    float m = fmaxf(v.x, v.y);
#pragma unroll
    for (int off = 1; off < 64; off <<= 1) m = fmaxf(m, __shfl_xor(m, off, 64));
    if (lane == 0) sm[wv] = m;
    __syncthreads();
    float gm = fmaxf(fmaxf(sm[0], sm[1]), fmaxf(sm[2], sm[3]));

    float e = expf(v.x - gm) + expf(v.y - gm);
#pragma unroll
    for (int off = 1; off < 64; off <<= 1) e += __shfl_xor(e, off, 64);
    if (lane == 0) ss[wv] = e;
    __syncthreads();
    if (tid == 0) {
        float2 o; o.x = gm; o.y = ss[0] + ss[1] + ss[2] + ss[3];
        *(float2*)&part[c * 2] = o;
    }
}

// ---------- log-softmax stage 2: combine partials inline, apply ----------
__global__ __launch_bounds__(256) void lsm_apply_kernel(
    const char* __restrict__ ws, float* __restrict__ out)
{
    const float4* s4 = (const float4*)(ws + WS_SCORE);
    const float* part = (const float*)(ws + WS_PART);
    __shared__ float sCC;
    const int tid = threadIdx.x;
    const int b = blockIdx.x >> 5;       // 32 blocks per batch
    if (tid < 64) {                      // inline combine of 64 partials
        float2 p = *(const float2*)&part[(b * 64 + tid) * 2];
        float gm = p.x;
#pragma unroll
        for (int off = 1; off < 64; off <<= 1) gm = fmaxf(gm, __shfl_xor(gm, off, 64));
        float l = p.y * expf(p.x - gm);
#pragma unroll
        for (int off = 1; off < 64; off <<= 1) l += __shfl_xor(l, off, 64);
        if (tid == 0) sCC = gm + logf(l);
    }
    __syncthreads();
    const float c = sCC;
    const int i = blockIdx.x * 256 + tid;    // 65536 float4s
    float4 v = s4[i];
    v.x -= c; v.y -= c; v.z -= c; v.w -= c;
    ((float4*)out)[i] = v;
}

extern "C" void kernel_launch(void* const* d_in, const int* in_sizes, int n_in,
                              void* d_out, int out_size, void* d_ws, size_t ws_size,
                              hipStream_t stream)
{
    const float* op_emb      = (const float*)d_in[0];
    const float* machine_emb = (const float*)d_in[1];
    const float* edge_emb    = (const float*)d_in[2];
    const int*   mask        = (const int*)  d_in[3];
    const float* W1 = (const float*)d_in[4];
    const float* b1 = (const float*)d_in[5];
    const float* W2 = (const float*)d_in[6];
    const float* b2 = (const float*)d_in[7];
    const float* W3 = (const float*)d_in[8];
    const float* b3 = (const float*)d_in[9];
    char* ws = (char*)d_ws;

    prep_kernel<<<48 + 1152, 256, 0, stream>>>(W1, W2, op_emb, machine_emb, b1, ws);
    main_kernel<<<(Bb * Nn) / Gg, 256, 0, stream>>>(edge_emb, mask, b2, W3, b3, ws);
    lsm_part_kernel<<<512, 256, 0, stream>>>(ws);
    lsm_apply_kernel<<<256, 256, 0, stream>>>(ws, (float*)d_out);
}

// Round 9
// 227.194 us; speedup vs baseline: 1.1767x; 1.0278x over previous
//
#include <hip/hip_runtime.h>
#include <math.h>

#define Bb 8
#define Nn 512
#define Mm 64
#define Dd 128
#define Hh 64
#define Gg 8                 // n's per block; grid = 4096/8 = 512 = 2 blocks/CU
#define NEG_BIG (-1.0e30f)

typedef __bf16 bf16x8 __attribute__((ext_vector_type(8)));
typedef float  f32x4  __attribute__((ext_vector_type(4)));

// ws byte offsets (16B-aligned)
#define WS_WEB   0u          // 16384 B  bf16 We B-frags, frag-linear [16 frag][64 lane][8]
#define WS_W2B   16384u      // 8192 B   bf16 W2 B-frags, frag-linear [8 frag][64 lane][8]
#define WS_CWSF  24576u      // 131072 B fp32 CwsF[b][w][t][lane][r] (b1 folded, frag-swizzled)
#define WS_AOP   155648u     // 1048576 B fp32 Aop[b*N+n][h]
#define WS_SCORE 1204224u    // 1048576 B fp32 scores[b*N+n][m]
#define WS_PART  2252800u    // 4096 B   fp32 (max,sumexp) per block [512][2]

// async global->LDS DMA, 16B/lane; offset must be an ICE -> fold into gp, pass 0
#define GLOAD_LDS(gp, lp) __builtin_amdgcn_global_load_lds( \
    (const __attribute__((address_space(1))) void*)(gp),    \
    (__attribute__((address_space(3))) void*)(lp), 16, 0, 0)

// ---------- prep: weight B-frags + projections (CwsF frag-swizzled) ----------
__global__ __launch_bounds__(256) void prep_kernel(
    const float* __restrict__ W1, const float* __restrict__ W2,
    const float* __restrict__ op_emb, const float* __restrict__ machine_emb,
    const float* __restrict__ b1, char* __restrict__ ws)
{
    if (blockIdx.x < 48) {               // weight fragment prep
        __bf16* WeB = (__bf16*)(ws + WS_WEB);
        __bf16* W2B = (__bf16*)(ws + WS_W2B);
        int idx = blockIdx.x * 256 + threadIdx.x;
        if (idx < 8192) {                // We: 16 frags (t 0..3, ks 0..3)
            int fid = idx >> 9, rem = idx & 511;
            int lane = rem >> 3, j = rem & 7;
            int t = fid >> 2, ks = fid & 3;
            int q = lane >> 4, ln = lane & 15;
            int d = ks * 32 + q * 8 + j;
            int h = t * 16 + ln;
            WeB[idx] = (__bf16)W1[(size_t)(2 * Dd + d) * Hh + h];
        } else {                         // W2: 8 frags (t 0..3, ks 0..1)
            int i2 = idx - 8192;
            int fid = i2 >> 9, rem = i2 & 511;
            int lane = rem >> 3, j = rem & 7;
            int t = fid >> 1, ks = fid & 1;
            int q = lane >> 4, ln = lane & 15;
            int k = ks * 32 + q * 8 + j;
            int h = t * 16 + ln;
            W2B[i2] = (__bf16)W2[(size_t)k * Hh + h];
        }
        return;
    }
    // projections: 1152 blocks x 4 rows (B*M + B*N = 4608 rows of 64)
    float* CwsF = (float*)(ws + WS_CWSF);
    float* Aop  = (float*)(ws + WS_AOP);
    const int bid = (blockIdx.x - 48) * 4 + (threadIdx.x >> 6);
    const int h = threadIdx.x & 63;
    if (bid < Bb * Mm) {
        const float* mg = machine_emb + (size_t)bid * Dd;
        const float* Wm = W1 + (size_t)Dd * Hh;
        float acc = b1[h];
#pragma unroll 8
        for (int d = 0; d < Dd; ++d) acc = fmaf(mg[d], Wm[d * Hh + h], acc);
        // scatter into fragment order: [b][w][t][lane=q*16+ln][r]
        int b = bid >> 6, m = bid & 63;
        int wq = m >> 4, q = (m >> 2) & 3, r = m & 3;
        int t = h >> 4, ln = h & 15;
        CwsF[((((b * 4 + wq) * 4 + t) * 64) + (q * 16 + ln)) * 4 + r] = acc;
    } else {
        const int bn = bid - Bb * Mm;
        const float* og = op_emb + (size_t)bn * Dd;
        float acc = 0.f;
#pragma unroll 8
        for (int d = 0; d < Dd; ++d) acc = fmaf(og[d], W1[d * Hh + h], acc);
        Aop[(size_t)bn * Hh + h] = acc;
    }
}

// ---------- main: DMA-streamed edge, weights+Cws in regs, fused softmax partials ----------
__global__ __launch_bounds__(256, 2) void main_kernel(
    const float* __restrict__ edge_emb, const int* __restrict__ mask,
    const float* __restrict__ b2, const float* __restrict__ W3,
    const float* __restrict__ b3, char* __restrict__ ws)
{
    __shared__ float  sEdge[4 * 2 * 2048];  // 65536 B: [wave][buf][seg 0..7][256 floats]
    __shared__ float  sAop[Gg * Hh];        //  2048 B
    __shared__ int    sMask[Gg * Mm];       //  2048 B
    __shared__ __bf16 sH1[Mm * 72];         //  9216 B
    __shared__ float  sRed[8];              //    32 B  -> ~79 KB, 2 blocks/CU

    float* scores = (float*)(ws + WS_SCORE);
    float* part   = (float*)(ws + WS_PART);

    const int tid  = threadIdx.x;
    const int lane = tid & 63;
    const int w    = tid >> 6;
    const int q    = lane >> 4;
    const int ln   = lane & 15;
    const int bn0  = blockIdx.x * Gg;
    const int b    = bn0 >> 9;              // 64 blocks per batch; never straddles
    const int wu   = __builtin_amdgcn_readfirstlane(w);   // SGPR wave id for LDS bases

    // per-lane global base: row m = w*16+ln, col q*8 (floats)
    const float* ebase = edge_emb + ((size_t)bn0 * Mm + w * 16 + ln) * Dd + q * 8;

    // ---- prologue DMAs: tiles g=0 -> buf0, g=1 -> buf1 (8 segs each) ----
    {
        float* d0 = &sEdge[(wu * 2 + 0) * 2048];
        float* d1 = &sEdge[(wu * 2 + 1) * 2048];
#pragma unroll
        for (int s = 0; s < 8; ++s)
            GLOAD_LDS(ebase + (s >> 1) * 32 + (s & 1) * 4, d0 + s * 256);
#pragma unroll
        for (int s = 0; s < 8; ++s)
            GLOAD_LDS(ebase + 8192 + (s >> 1) * 32 + (s & 1) * 4, d1 + s * 256);
    }

    // ---- one-time staging (linear/coalesced) ----
    if (tid < 128) {
        ((f32x4*)sAop)[tid] = ((const f32x4*)(ws + WS_AOP))[(size_t)bn0 * 16 + tid];
        ((int4*)sMask)[tid] = ((const int4*)mask)[(size_t)bn0 * 16 + tid];
    }

    // ---- weights + Cws tile into registers (held whole kernel) ----
    bf16x8 weF[16], w2F[8];
    f32x4  cv[4];
    {
        const bf16x8* WeB = (const bf16x8*)(ws + WS_WEB);
        const bf16x8* W2B = (const bf16x8*)(ws + WS_W2B);
#pragma unroll
        for (int f = 0; f < 16; ++f) weF[f] = WeB[f * 64 + lane];
#pragma unroll
        for (int f = 0; f < 8; ++f)  w2F[f] = W2B[f * 64 + lane];
        const f32x4* CwsF = (const f32x4*)(ws + WS_CWSF) + (size_t)b * 1024;
#pragma unroll
        for (int t = 0; t < 4; ++t)  cv[t] = CwsF[(w * 4 + t) * 64 + lane];
    }

    float b2v[4], w3v[4];
#pragma unroll
    for (int t = 0; t < 4; ++t) { b2v[t] = b2[t * 16 + ln]; w3v[t] = W3[t * 16 + ln]; }
    const float bias3 = b3[0];

    float m_loc = NEG_BIG, l_loc = 0.f;     // per-lane online softmax state

    __syncthreads();   // staging visible (drains prologue DMAs too)

#pragma unroll
    for (int g = 0; g < Gg; ++g) {
        const int buf = g & 1;
        const float* ldsrd = &sEdge[(wu * 2 + buf) * 2048];

        // drain only the tile being consumed; keep in-flight refill pending
        if (g == Gg - 1) __builtin_amdgcn_s_waitcnt(0x0F70);  // vmcnt(0) at tail
        else             __builtin_amdgcn_s_waitcnt(0x0F78);  // vmcnt(8)

        f32x4 lo[4], hi[4];
#pragma unroll
        for (int ks = 0; ks < 4; ++ks) {
            lo[ks] = *(const f32x4*)&ldsrd[(ks * 2 + 0) * 256 + lane * 4];
            hi[ks] = *(const f32x4*)&ldsrd[(ks * 2 + 1) * 256 + lane * 4];
        }
        bf16x8 af[4];
#pragma unroll
        for (int ks = 0; ks < 4; ++ks) {
            bf16x8 a;
            a[0] = (__bf16)lo[ks][0]; a[1] = (__bf16)lo[ks][1];
            a[2] = (__bf16)lo[ks][2]; a[3] = (__bf16)lo[ks][3];
            a[4] = (__bf16)hi[ks][0]; a[5] = (__bf16)hi[ks][1];
            a[6] = (__bf16)hi[ks][2]; a[7] = (__bf16)hi[ks][3];
            af[ks] = a;
        }

        // refill this buffer with tile g+2
        if (g + 2 < Gg) {
            float* dst = &sEdge[(wu * 2 + buf) * 2048];
            const float* src = ebase + (size_t)(g + 2) * 8192;
#pragma unroll
            for (int s = 0; s < 8; ++s)
                GLOAD_LDS(src + (s >> 1) * 32 + (s & 1) * 4, dst + s * 256);
        }

        // acc init = Aop[n,h] + Cws[m,h]
        f32x4 acc[4];
#pragma unroll
        for (int t = 0; t < 4; ++t) {
            float av = sAop[g * Hh + t * 16 + ln];
            acc[t][0] = cv[t][0] + av; acc[t][1] = cv[t][1] + av;
            acc[t][2] = cv[t][2] + av; acc[t][3] = cv[t][3] + av;
        }

        // GEMM1: D = edge . We + (A+C)
#pragma unroll
        for (int t = 0; t < 4; ++t)
#pragma unroll
            for (int ks = 0; ks < 4; ++ks)
                acc[t] = __builtin_amdgcn_mfma_f32_16x16x32_bf16(af[ks], weF[t * 4 + ks], acc[t], 0, 0, 0);

        // epilogue 1: relu -> sH1 (wave-private rows, no barrier)
#pragma unroll
        for (int t = 0; t < 4; ++t)
#pragma unroll
            for (int r = 0; r < 4; ++r)
                sH1[(w * 16 + q * 4 + r) * 72 + t * 16 + ln] =
                    (__bf16)fmaxf(acc[t][r], 0.f);

        // GEMM2
        bf16x8 a2[2];
#pragma unroll
        for (int ks = 0; ks < 2; ++ks)
            a2[ks] = *(const bf16x8*)&sH1[(w * 16 + ln) * 72 + ks * 32 + q * 8];
        f32x4 c2[4];
#pragma unroll
        for (int t = 0; t < 4; ++t) c2[t] = (f32x4){0.f, 0.f, 0.f, 0.f};
#pragma unroll
        for (int t = 0; t < 4; ++t)
#pragma unroll
            for (int ks = 0; ks < 2; ++ks)
                c2[t] = __builtin_amdgcn_mfma_f32_16x16x32_bf16(a2[ks], w2F[t * 2 + ks], c2[t], 0, 0, 0);

        // epilogue 2: masked scores + online softmax partials
        float p[4] = {0.f, 0.f, 0.f, 0.f};
#pragma unroll
        for (int t = 0; t < 4; ++t)
#pragma unroll
            for (int r = 0; r < 4; ++r)
                p[r] += fmaxf(c2[t][r] + b2v[t], 0.f) * w3v[t];
#pragma unroll
        for (int r = 0; r < 4; ++r) {
            p[r] += __shfl_xor(p[r], 1, 64);
            p[r] += __shfl_xor(p[r], 2, 64);
            p[r] += __shfl_xor(p[r], 4, 64);
            p[r] += __shfl_xor(p[r], 8, 64);
        }
        // after reduce, all 16 ln-lanes of a q-group hold identical p[0..3]
        const int m0 = w * 16 + q * 4;
        const int* mrow = &sMask[g * Mm + m0];
        float vv[4];
#pragma unroll
        for (int r = 0; r < 4; ++r) {
            float v = p[r] + bias3;
            vv[r] = mrow[r] ? v : NEG_BIG;
            if (mrow[r]) {                  // online update with valid entries only
                float mn = fmaxf(m_loc, v);
                l_loc = l_loc * expf(m_loc - mn) + expf(v - mn);
                m_loc = mn;
            }
        }
        if (ln == 0) {
            float4 o; o.x = vv[0]; o.y = vv[1]; o.z = vv[2]; o.w = vv[3];
            *(float4*)&scores[(size_t)(bn0 + g) * Mm + m0] = o;
        }
    }

    // ---- block softmax partial: combine q-groups (xor 16,32), then waves ----
#pragma unroll
    for (int off = 16; off <= 32; off <<= 1) {
        float mo = __shfl_xor(m_loc, off, 64);
        float lo2 = __shfl_xor(l_loc, off, 64);
        float mn = fmaxf(m_loc, mo);
        l_loc = l_loc * expf(m_loc - mn) + lo2 * expf(mo - mn);
        m_loc = mn;
    }
    if (lane == 0) { sRed[w * 2] = m_loc; sRed[w * 2 + 1] = l_loc; }
    __syncthreads();
    if (tid == 0) {
        float gm = sRed[0], gl = sRed[1];
#pragma unroll
        for (int k = 1; k < 4; ++k) {
            float mo = sRed[k * 2], lo2 = sRed[k * 2 + 1];
            float mn = fmaxf(gm, mo);
            gl = gl * expf(gm - mn) + lo2 * expf(mo - mn);
            gm = mn;
        }
        float2 o; o.x = gm; o.y = gl;
        *(float2*)&part[blockIdx.x * 2] = o;
    }
}

// ---------- log-softmax: combine 64 partials per batch inline, apply ----------
__global__ __launch_bounds__(256) void lsm_apply_kernel(
    const char* __restrict__ ws, float* __restrict__ out)
{
    const float4* s4 = (const float4*)(ws + WS_SCORE);
    const float* part = (const float*)(ws + WS_PART);
    __shared__ float sCC;
    const int tid = threadIdx.x;
    const int b = blockIdx.x >> 5;       // 32 blocks per batch
    if (tid < 64) {                      // inline combine of 64 partials
        float2 p = *(const float2*)&part[(b * 64 + tid) * 2];
        float gm = p.x;
#pragma unroll
        for (int off = 1; off < 64; off <<= 1) gm = fmaxf(gm, __shfl_xor(gm, off, 64));
        float l = p.y * expf(p.x - gm);
#pragma unroll
        for (int off = 1; off < 64; off <<= 1) l += __shfl_xor(l, off, 64);
        if (tid == 0) sCC = gm + logf(l);
    }
    __syncthreads();
    const float c = sCC;
    const int i = blockIdx.x * 256 + tid;    // 65536 float4s
    float4 v = s4[i];
    v.x -= c; v.y -= c; v.z -= c; v.w -= c;
    ((float4*)out)[i] = v;
}

extern "C" void kernel_launch(void* const* d_in, const int* in_sizes, int n_in,
                              void* d_out, int out_size, void* d_ws, size_t ws_size,
                              hipStream_t stream)
{
    const float* op_emb      = (const float*)d_in[0];
    const float* machine_emb = (const float*)d_in[1];
    const float* edge_emb    = (const float*)d_in[2];
    const int*   mask        = (const int*)  d_in[3];
    const float* W1 = (const float*)d_in[4];
    const float* b1 = (const float*)d_in[5];
    const float* W2 = (const float*)d_in[6];
    const float* b2 = (const float*)d_in[7];
    const float* W3 = (const float*)d_in[8];
    const float* b3 = (const float*)d_in[9];
    char* ws = (char*)d_ws;

    prep_kernel<<<48 + 1152, 256, 0, stream>>>(W1, W2, op_emb, machine_emb, b1, ws);
    main_kernel<<<(Bb * Nn) / Gg, 256, 0, stream>>>(edge_emb, mask, b2, W3, b3, ws);
    lsm_apply_kernel<<<256, 256, 0, stream>>>(ws, (float*)d_out);
}